// Round 13
// baseline (1017.397 us; speedup 1.0000x reference)
//
#include <hip/hip_runtime.h>
#include <hip/hip_bf16.h>
#include <math.h>

// Problem constants (Qwen3 MoE block)
#define T_TOK 2048
#define H_DIM 2048
#define NEXP  64
#define TOPK  8
#define I_DIM 768
#define CAPE  512
#define MTMAX 4   // CAPE/128
#define LDW   40  // padded B stride (shorts); multiple of 8 (16B) for b128 alignment

typedef short bf16x8 __attribute__((ext_vector_type(8)));
typedef float f32x4  __attribute__((ext_vector_type(4)));

__device__ __forceinline__ unsigned short f2bf(float f) {
  unsigned u = __float_as_uint(f);
  u += 0x7fffu + ((u >> 16) & 1u);   // RNE
  return (unsigned short)(u >> 16);
}
__device__ __forceinline__ float bf2f(unsigned short b) {
  return __uint_as_float(((unsigned)b) << 16);
}
__device__ __forceinline__ unsigned pack2(float lo, float hi) {
  __hip_bfloat162 h = __float22bfloat162_rn(make_float2(lo, hi));  // v_cvt_pk_bf16_f32
  unsigned r; __builtin_memcpy(&r, &h, 4); return r;
}
// Async global->LDS, 16B per lane. Dest = wave-uniform base + lane*16 (HW rule).
__device__ __forceinline__ void async16(void* lds, const unsigned short* g) {
  __builtin_amdgcn_global_load_lds(
      (const __attribute__((address_space(1))) unsigned int*)(const void*)g,
      (__attribute__((address_space(3))) unsigned int*)lds, 16, 0, 0);
}

// ---------------- K0: x -> bf16 (one-time; numerics identical) -------------
__global__ __launch_bounds__(256) void k_xcvt(const float* __restrict__ x,
                                              unsigned short* __restrict__ xb) {
  const size_t i = ((size_t)blockIdx.x * 256 + threadIdx.x) * 8;
  float4 p = *(const float4*)(x + i);
  float4 q = *(const float4*)(x + i + 4);
  union { unsigned u[4]; bf16x8 v; } r;
  r.u[0] = pack2(p.x, p.y); r.u[1] = pack2(p.z, p.w);
  r.u[2] = pack2(q.x, q.y); r.u[3] = pack2(q.z, q.w);
  *(bf16x8*)(xb + i) = r.v;
}

// ---------------- K1: router logits + softmax-top8 + renorm (fp32) ---------
__global__ __launch_bounds__(256) void k_router(const float* __restrict__ x,
                                                const float* __restrict__ wr,
                                                int* __restrict__ topk_idx,
                                                float* __restrict__ topk_w) {
  const int lane = threadIdx.x & 63;
  const int t = blockIdx.x * 4 + (threadIdx.x >> 6);
  const float4* xr   = (const float4*)(x + (size_t)t * H_DIM);
  const float4* wrow = (const float4*)(wr + (size_t)lane * H_DIM);
  float acc = 0.f;                       // matches reference fp32 dot
  for (int i = 0; i < H_DIM / 4; ++i) {
    float4 a = xr[i], b = wrow[i];
    acc = fmaf(a.x, b.x, acc); acc = fmaf(a.y, b.y, acc);
    acc = fmaf(a.z, b.z, acc); acc = fmaf(a.w, b.w, acc);
  }
  float cur = acc;
  float val[TOPK]; int idx[TOPK];
#pragma unroll
  for (int r = 0; r < TOPK; ++r) {
    float bv = cur; int bi = lane;
#pragma unroll
    for (int off = 32; off > 0; off >>= 1) {   // argmax, ties -> lower index
      float ov = __shfl_xor(bv, off);
      int   oi = __shfl_xor(bi, off);
      if (ov > bv || (ov == bv && oi < bi)) { bv = ov; bi = oi; }
    }
    val[r] = bv; idx[r] = bi;
    if (lane == bi) cur = -INFINITY;
  }
  float m = val[0], s = 0.f, w[TOPK];
#pragma unroll
  for (int r = 0; r < TOPK; ++r) { w[r] = expf(val[r] - m); s += w[r]; }
  if (lane < TOPK) {
    topk_idx[t * TOPK + lane] = idx[lane];
    topk_w [t * TOPK + lane] = w[lane] / s;
  }
}

// ---------------- K2: stable rank within expert (4 chunks in flight) -------
__global__ __launch_bounds__(1024) void k_rank(const int* __restrict__ topk_idx,
                                               int* __restrict__ pair_pos,
                                               int* __restrict__ slot_token,
                                               int* __restrict__ cnts) {
  __shared__ int s_run[64];
  __shared__ int s_whist[16][64];
  const int tid = threadIdx.x, lane = tid & 63, wv = tid >> 6;   // wv in [0,16)
  const int sub = wv >> 2;                 // chunk-in-flight 0..3
  if (tid < 64) s_run[tid] = 0;
  for (int it = 0; it < 16; ++it) {
    const int p = (it * 4 + sub) * 256 + (tid & 255);
    const int e = topk_idx[p];
    __syncthreads();
    s_whist[wv][lane] = 0;
    __syncthreads();
    unsigned long long m = ~0ull;
#pragma unroll
    for (int b = 0; b < 6; ++b) {
      unsigned long long bb = __ballot((e >> b) & 1);
      m &= ((e >> b) & 1) ? bb : ~bb;
    }
    const int rw = __popcll(m & ((1ull << lane) - 1ull));
    if (rw == 0) s_whist[wv][e] = __popcll(m);
    __syncthreads();
    int off = rw;
    for (int w2 = 0; w2 < wv; ++w2) off += s_whist[w2][e];
    const int pos = s_run[e] + off;
    pair_pos[p] = pos;
    if (pos < CAPE) slot_token[e * CAPE + pos] = p >> 3;
    __syncthreads();
    if (tid < 64) {
      int tsum = 0;
#pragma unroll
      for (int w2 = 0; w2 < 16; ++w2) tsum += s_whist[w2][tid];
      s_run[tid] += tsum;
    }
  }
  __syncthreads();
  if (tid < 64) cnts[tid] = s_run[tid];
}

// ---------------- K3: fused gate+up GEMM + SwiGLU -> act (bf16) ------------
// Champion skeleton + async A-path: A tiles via global_load_lds into 4-deep
// linear [128][32] LDS buffers (issued 2 tiles ahead); B unchanged (fp32->bf16
// pack into padded LDW=40 tiles).
__global__ __launch_bounds__(512) void k_gateup(const unsigned short* __restrict__ xb,
                                                const float* __restrict__ wg,
                                                const float* __restrict__ wu,
                                                const int* __restrict__ slot_token,
                                                const int* __restrict__ cnts,
                                                unsigned short* __restrict__ act) {
  const int NB = NEXP * MTMAX * 6;
  const int v = (blockIdx.x & 7) * (NB / 8) + (blockIdx.x >> 3);  // XCD chunk swizzle
  const int e = v / (MTMAX * 6);
  const int rem = v % (MTMAX * 6);
  const int mt = rem / 6, nt = rem % 6;

  int cnt = cnts[e]; cnt = cnt < CAPE ? cnt : CAPE;
  if (cnt <= 0 || mt * 128 >= cnt) return;
  const int m0 = mt << 7;

  __shared__ __align__(16) short Asl[4][128 * 32];   // 32 KiB linear (async dest)
  __shared__ __align__(16) short Bg[2][128 * LDW];   // 20 KiB
  __shared__ __align__(16) short Bu[2][128 * LDW];   // 20 KiB

  const int tid = threadIdx.x;
  const int lane = tid & 63, wave = tid >> 6;
  const int wm = wave >> 2, wn = wave & 3;       // 2x4 wave grid, 64x32 tiles
  const int lr = lane & 15, lg = lane >> 4;

  // A async staging: wave w owns rows w*16..+15; lane -> (row w*16+(lane>>2),
  // col (lane&3)*8). HW dest = base + lane*16B matches row-major [16][32].
  const int arow = wave * 16 + (lane >> 2);
  const int tokA = (m0 + arow < cnt) ? slot_token[e * CAPE + m0 + arow] : 0;
  const unsigned short* axg = xb + (size_t)tokA * H_DIM + (lane & 3) * 8;

  // B staging: one matrix per thread-half; kq = idx&7 (rows 4kq..+3),
  // nq = idx>>3 (cols 4nq..+3); conflict-free b64 transpose writes.
  const int b_mat = tid >> 8;
  const int b_idx = tid & 255;
  const int b_kq = b_idx & 7, b_nq = b_idx >> 3;
  const size_t wbase = (size_t)e * H_DIM * I_DIM + (size_t)nt * 128;
  const float* bp  = (b_mat ? wu : wg) + wbase + (size_t)(4 * b_kq) * I_DIM + 4 * b_nq;
  short* Bdst0 = b_mat ? Bu[0] : Bg[0];
  short* Bdst1 = b_mat ? Bu[1] : Bg[1];

  f32x4 accg[4][2], accu[4][2];
#pragma unroll
  for (int mi = 0; mi < 4; ++mi)
#pragma unroll
    for (int ni = 0; ni < 2; ++ni) {
      accg[mi][ni] = (f32x4){0.f, 0.f, 0.f, 0.f};
      accu[mi][ni] = (f32x4){0.f, 0.f, 0.f, 0.f};
    }

  struct Tile { float4 b[4]; };

  auto ALOAD = [&](int j, int kt) {       // issue async A copy for tile kt
    async16(&Asl[j][wave * 512], axg + (size_t)kt * 32);
  };
  auto LOADB = [&](Tile& Tl, int kt) {
    const float* r0 = bp + (size_t)(kt * 32) * I_DIM;
#pragma unroll
    for (int j = 0; j < 4; ++j)
      Tl.b[j] = *(const float4*)(r0 + (size_t)j * I_DIM);
  };
  auto STOREB = [&](const Tile& Tl, int b) {
    short* Bd = b ? Bdst1 : Bdst0;
    const float* q0 = (const float*)&Tl.b[0];
    const float* q1 = (const float*)&Tl.b[1];
    const float* q2 = (const float*)&Tl.b[2];
    const float* q3 = (const float*)&Tl.b[3];
#pragma unroll
    for (int i = 0; i < 4; ++i) {
      uint2 w = { pack2(q0[i], q1[i]), pack2(q2[i], q3[i]) };  // k 4kq..4kq+3
      *(uint2*)(&Bd[(4 * b_nq + i) * LDW + 4 * b_kq]) = w;
    }
  };
  auto COMPUTE = [&](int ja, int jb) {
    bf16x8 a[4], bg[2], bu[2];
#pragma unroll
    for (int mi = 0; mi < 4; ++mi)
      a[mi] = *(const bf16x8*)(&Asl[ja][(wm * 64 + mi * 16 + lr) * 32 + lg * 8]);
#pragma unroll
    for (int ni = 0; ni < 2; ++ni) {
      bg[ni] = *(const bf16x8*)(&Bg[jb][(wn * 32 + ni * 16 + lr) * LDW + lg * 8]);
      bu[ni] = *(const bf16x8*)(&Bu[jb][(wn * 32 + ni * 16 + lr) * LDW + lg * 8]);
    }
#pragma unroll
    for (int mi = 0; mi < 4; ++mi)
#pragma unroll
      for (int ni = 0; ni < 2; ++ni) {
        accg[mi][ni] = __builtin_amdgcn_mfma_f32_16x16x32_bf16(a[mi], bg[ni], accg[mi][ni], 0, 0, 0);
        accu[mi][ni] = __builtin_amdgcn_mfma_f32_16x16x32_bf16(a[mi], bu[ni], accu[mi][ni], 0, 0, 0);
      }
  };

  const int NK = H_DIM / 32;   // 64 (divisible by 4)
  Tile tA, tB;
  ALOAD(0, 0); ALOAD(1, 1);
  LOADB(tA, 0); STOREB(tA, 0);
  LOADB(tB, 1);
  __syncthreads();             // drains A0,A1 into LDS

#pragma unroll 1
  for (int t = 0; t + 7 < NK; t += 4) {
    ALOAD(2, t + 2); LOADB(tA, t + 2);
    COMPUTE(0, 0); STOREB(tB, 1); __syncthreads();
    ALOAD(3, t + 3); LOADB(tB, t + 3);
    COMPUTE(1, 1); STOREB(tA, 0); __syncthreads();
    ALOAD(0, t + 4); LOADB(tA, t + 4);
    COMPUTE(2, 0); STOREB(tB, 1); __syncthreads();
    ALOAD(1, t + 5); LOADB(tB, t + 5);
    COMPUTE(3, 1); STOREB(tA, 0); __syncthreads();
  }
  // epilogue: tiles NK-4..NK-1 (A bufs 0..3, B parity starts even)
  ALOAD(2, NK - 2); LOADB(tA, NK - 2);
  COMPUTE(0, 0); STOREB(tB, 1); __syncthreads();
  ALOAD(3, NK - 1); LOADB(tB, NK - 1);
  COMPUTE(1, 1); STOREB(tA, 0); __syncthreads();
  COMPUTE(2, 0); STOREB(tB, 1); __syncthreads();
  COMPUTE(3, 1);

  // epilogue: silu(g)*u -> bf16 act
#pragma unroll
  for (int mi = 0; mi < 4; ++mi)
#pragma unroll
    for (int ni = 0; ni < 2; ++ni)
#pragma unroll
      for (int r = 0; r < 4; ++r) {
        const int row = m0 + wm * 64 + mi * 16 + lg * 4 + r;
        const int col = nt * 128 + wn * 32 + ni * 16 + lr;
        const float g = accg[mi][ni][r], u = accu[mi][ni][r];
        const float vv = (g / (1.f + __expf(-g))) * u;
        act[(size_t)(e * CAPE + row) * I_DIM + col] = f2bf(vv);
      }
}

// ---------------- K4: down GEMM -> y (bf16) --------------------------------
// Async A-path (act bf16, contiguous rows) + B by waves 0-3. LDS 52 KiB ->
// 3 blocks/CU.
__global__ __launch_bounds__(512, 6) void k_down(const unsigned short* __restrict__ act,
                                                 const float* __restrict__ wd,
                                                 const int* __restrict__ cnts,
                                                 unsigned short* __restrict__ y) {
  const int NB = NEXP * MTMAX * 16;
  const int v = (blockIdx.x & 7) * (NB / 8) + (blockIdx.x >> 3);
  const int e = v / (MTMAX * 16);
  const int rem = v % (MTMAX * 16);
  const int mt = rem / 16, nt = rem % 16;

  int cnt = cnts[e]; cnt = cnt < CAPE ? cnt : CAPE;
  if (cnt <= 0 || mt * 128 >= cnt) return;
  const int m0 = mt << 7;

  __shared__ __align__(16) short Asl[4][128 * 32];   // 32 KiB linear (async dest)
  __shared__ __align__(16) short Bt[2][128 * LDW];   // 20 KiB

  const int tid = threadIdx.x;
  const int lane = tid & 63, wave = tid >> 6;
  const int wm = wave >> 2, wn = wave & 3;
  const int lr = lane & 15, lg = lane >> 4;

  const int arow = wave * 16 + (lane >> 2);
  const unsigned short* apg = act + (size_t)(e * CAPE + m0 + arow) * I_DIM + (lane & 3) * 8;

  const int b_kq = tid & 7, b_nq = (tid >> 3) & 31;   // valid for tid<256
  const bool bstage = (tid < 256);
  const size_t wbase = (size_t)e * I_DIM * H_DIM + (size_t)nt * 128;
  const float* bp = wd + wbase + (size_t)(4 * b_kq) * H_DIM + 4 * b_nq;

  f32x4 acc[4][2];
#pragma unroll
  for (int mi = 0; mi < 4; ++mi)
#pragma unroll
    for (int ni = 0; ni < 2; ++ni) acc[mi][ni] = (f32x4){0.f, 0.f, 0.f, 0.f};

  struct Tile { float4 b[4]; };

  auto ALOAD = [&](int j, int kt) {
    async16(&Asl[j][wave * 512], apg + (size_t)kt * 32);
  };
  auto LOADB = [&](Tile& Tl, int kt) {
    if (!bstage) return;
    const float* r0 = bp + (size_t)(kt * 32) * H_DIM;
#pragma unroll
    for (int j = 0; j < 4; ++j)
      Tl.b[j] = *(const float4*)(r0 + (size_t)j * H_DIM);
  };
  auto STOREB = [&](const Tile& Tl, int b) {
    if (!bstage) return;
    const float* q0 = (const float*)&Tl.b[0];
    const float* q1 = (const float*)&Tl.b[1];
    const float* q2 = (const float*)&Tl.b[2];
    const float* q3 = (const float*)&Tl.b[3];
#pragma unroll
    for (int i = 0; i < 4; ++i) {
      uint2 w = { pack2(q0[i], q1[i]), pack2(q2[i], q3[i]) };  // k 4kq..4kq+3
      *(uint2*)(&Bt[b][(4 * b_nq + i) * LDW + 4 * b_kq]) = w;
    }
  };
  auto COMPUTE = [&](int ja, int jb) {
    bf16x8 a[4], bb[2];
#pragma unroll
    for (int mi = 0; mi < 4; ++mi)
      a[mi] = *(const bf16x8*)(&Asl[ja][(wm * 64 + mi * 16 + lr) * 32 + lg * 8]);
#pragma unroll
    for (int ni = 0; ni < 2; ++ni)
      bb[ni] = *(const bf16x8*)(&Bt[jb][(wn * 32 + ni * 16 + lr) * LDW + lg * 8]);
#pragma unroll
    for (int mi = 0; mi < 4; ++mi)
#pragma unroll
      for (int ni = 0; ni < 2; ++ni)
        acc[mi][ni] = __builtin_amdgcn_mfma_f32_16x16x32_bf16(a[mi], bb[ni], acc[mi][ni], 0, 0, 0);
  };

  const int NK = I_DIM / 32;   // 24 (divisible by 4)
  Tile tA, tB;
  ALOAD(0, 0); ALOAD(1, 1);
  LOADB(tA, 0); STOREB(tA, 0);
  LOADB(tB, 1);
  __syncthreads();

#pragma unroll 1
  for (int t = 0; t + 7 < NK; t += 4) {
    ALOAD(2, t + 2); LOADB(tA, t + 2);
    COMPUTE(0, 0); STOREB(tB, 1); __syncthreads();
    ALOAD(3, t + 3); LOADB(tB, t + 3);
    COMPUTE(1, 1); STOREB(tA, 0); __syncthreads();
    ALOAD(0, t + 4); LOADB(tA, t + 4);
    COMPUTE(2, 0); STOREB(tB, 1); __syncthreads();
    ALOAD(1, t + 5); LOADB(tB, t + 5);
    COMPUTE(3, 1); STOREB(tA, 0); __syncthreads();
  }
  ALOAD(2, NK - 2); LOADB(tA, NK - 2);
  COMPUTE(0, 0); STOREB(tB, 1); __syncthreads();
  ALOAD(3, NK - 1); LOADB(tB, NK - 1);
  COMPUTE(1, 1); STOREB(tA, 0); __syncthreads();
  COMPUTE(2, 0); STOREB(tB, 1); __syncthreads();
  COMPUTE(3, 1);

#pragma unroll
  for (int mi = 0; mi < 4; ++mi)
#pragma unroll
    for (int ni = 0; ni < 2; ++ni)
#pragma unroll
      for (int r = 0; r < 4; ++r) {
        const int row = m0 + wm * 64 + mi * 16 + lg * 4 + r;
        const int col = nt * 128 + wn * 32 + ni * 16 + lr;
        y[(size_t)(e * CAPE + row) * H_DIM + col] = f2bf(acc[mi][ni][r]);
      }
}

// ---------------- K5: combine (deterministic gather) -----------------------
__global__ __launch_bounds__(256) void k_combine(const unsigned short* __restrict__ y,
                                                 const int* __restrict__ topk_idx,
                                                 const float* __restrict__ topk_w,
                                                 const int* __restrict__ pair_pos,
                                                 float* __restrict__ out) {
  const int t = blockIdx.x;
  __shared__ int s_e[TOPK]; __shared__ int s_p[TOPK]; __shared__ float s_w[TOPK];
  if (threadIdx.x < TOPK) {
    s_e[threadIdx.x] = topk_idx[t * TOPK + threadIdx.x];
    s_p[threadIdx.x] = pair_pos[t * TOPK + threadIdx.x];
    s_w[threadIdx.x] = topk_w [t * TOPK + threadIdx.x];
  }
  __syncthreads();
  const int h0 = threadIdx.x * 8;
  float acc[8] = {0.f, 0.f, 0.f, 0.f, 0.f, 0.f, 0.f, 0.f};
#pragma unroll
  for (int k = 0; k < TOPK; ++k) {
    const int pos = s_p[k];
    if (pos >= CAPE) continue;
    const float w = s_w[k];
    const bf16x8 vv = *(const bf16x8*)(&y[(size_t)(s_e[k] * CAPE + pos) * H_DIM + h0]);
#pragma unroll
    for (int j = 0; j < 8; ++j) acc[j] += w * bf2f((unsigned short)vv[j]);
  }
  float4 o0 = {acc[0], acc[1], acc[2], acc[3]};
  float4 o1 = {acc[4], acc[5], acc[6], acc[7]};
  *(float4*)(out + (size_t)t * H_DIM + h0)     = o0;
  *(float4*)(out + (size_t)t * H_DIM + h0 + 4) = o1;
}

// ---------------------------------------------------------------------------
extern "C" void kernel_launch(void* const* d_in, const int* in_sizes, int n_in,
                              void* d_out, int out_size, void* d_ws, size_t ws_size,
                              hipStream_t stream) {
  const float* x   = (const float*)d_in[0];
  const float* wr  = (const float*)d_in[1];
  const float* wgt = (const float*)d_in[2];
  const float* wup = (const float*)d_in[3];
  const float* wdn = (const float*)d_in[4];
  float* out = (float*)d_out;

  char* ws = (char*)d_ws;
  int*            topk_idx   = (int*)(ws);                    //  64 KiB
  float*          topk_w     = (float*)(ws + 65536);          //  64 KiB
  int*            pair_pos   = (int*)(ws + 131072);           //  64 KiB
  int*            cnts       = (int*)(ws + 196608);           // 256 B
  int*            slot_token = (int*)(ws + 196864);           // 128 KiB
  unsigned short* xb         = (unsigned short*)(ws + 327936);            //  8 MiB
  unsigned short* act        = (unsigned short*)(ws + 327936 + 8388608);  // 48 MiB
  unsigned short* yb         = (unsigned short*)(ws + 327936 + 8388608 + 50331648); // 128 MiB

  k_xcvt   <<<dim3(T_TOK * H_DIM / 2048), dim3(256), 0, stream>>>(x, xb);
  k_router <<<dim3(T_TOK / 4),        dim3(256), 0, stream>>>(x, wr, topk_idx, topk_w);
  k_rank   <<<dim3(1),                dim3(1024), 0, stream>>>(topk_idx, pair_pos, slot_token, cnts);
  k_gateup <<<dim3(NEXP * MTMAX * 6), dim3(512), 0, stream>>>(xb, wgt, wup, slot_token, cnts, act);
  k_down   <<<dim3(NEXP * MTMAX * 16),dim3(512), 0, stream>>>(act, wdn, cnts, yb);
  k_combine<<<dim3(T_TOK),            dim3(256), 0, stream>>>(yb, topk_idx, topk_w, pair_pos, out);
}